// Round 1
// baseline (253.020 us; speedup 1.0000x reference)
//
#include <hip/hip_runtime.h>
#include <math.h>

#define LOG2E 1.44269504088896f
constexpr int CD  = 256;          // C
constexpr int NS  = 16;           // N states
constexpr int RE  = 4;            // R repeats
constexpr int Bb  = 2;            // batch
constexpr int LL  = 4096;         // L
constexpr int BLr = Bb*LL;        // 8192 rows
constexpr int SCX = 288;          // ssm cols = C + 2N
constexpr int TC  = 16;           // chunk length (steps)
constexpr int JC  = LL/TC;        // 256 chunks per rep
constexpr int GS  = 16;           // combine group size
constexpr int GNg = JC/GS;        // 16 groups

__device__ __forceinline__ float softplus_f(float v){
  return fmaxf(v, 0.f) + log1pf(__expf(-fabsf(v)));
}
__device__ __forceinline__ float silu_f(float v){
  return v * (1.f/(1.f + __expf(-v)));
}

// ---------------- per-row mean/rstd ----------------
__global__ __launch_bounds__(256) void row_stats(const float* __restrict__ X,
                                                 float* __restrict__ stats){
  int row  = blockIdx.x*4 + (threadIdx.x >> 6);
  int lane = threadIdx.x & 63;
  float4 v = reinterpret_cast<const float4*>(X + row*CD)[lane];
  float s  = v.x+v.y+v.z+v.w;
  float s2 = v.x*v.x+v.y*v.y+v.z*v.z+v.w*v.w;
  #pragma unroll
  for (int off = 32; off > 0; off >>= 1){
    s  += __shfl_down(s, off);
    s2 += __shfl_down(s2, off);
  }
  if (lane == 0){
    float m   = s*(1.f/CD);
    float var = s2*(1.f/CD) - m*m;
    stats[row*2+0] = m;
    stats[row*2+1] = rsqrtf(var + 1e-5f);
  }
}

// ---------------- tiled fp32 GEMM with fused A-transform + epilogue ----------------
// MODE 0: A = LN(x) on the fly; epi: silu(v+b); cols<256 -> out0 (xg), else out1 (z)
// MODE 1: A = raw xg;           epi: v+b -> out0 (ssm, stride 288, col-masked)
// MODE 2: A = z*LN(y);          epi: v+b+resid -> out0 (final out)
template<int MODE, int TM, int TN>
__global__ __launch_bounds__(256) void gemm_k(
    const float* __restrict__ A0, const float* __restrict__ A1,
    const float* __restrict__ Bm, const float* __restrict__ bias,
    const float* __restrict__ stats, const float* __restrict__ lnsc,
    const float* __restrict__ lnbi, const float* __restrict__ resid,
    float* __restrict__ out0, float* __restrict__ out1, int Nw)
{
  constexpr int BM = 16*TM, BN = 16*TN, BK = 32;
  constexpr int ASL = BM+4, BSL = BN+4;
  __shared__ float As[BK*ASL];
  __shared__ float Bs[BK*BSL];
  const int tid = threadIdx.x;
  const int tx = tid & 15, ty = tid >> 4;
  const int n0 = blockIdx.x * BN, m0 = blockIdx.y * BM;

  float acc[TM][TN];
  #pragma unroll
  for (int i=0;i<TM;i++)
    #pragma unroll
    for (int j=0;j<TN;j++) acc[i][j] = 0.f;

  const int k4  = tid & 7;   // A staging: float4 col within BK
  const int mr0 = tid >> 3;  // A staging: row 0..31
  const int n4  = tid & 31;  // B staging: float4 col within BN
  const int kr0 = tid >> 5;  // B staging: row 0..7

  for (int k0 = 0; k0 < CD; k0 += BK){
    float4 av[BM/32];
    #pragma unroll
    for (int p=0;p<BM/32;p++){
      int m = mr0 + p*32;
      int row = m0 + m;
      float4 xv = *reinterpret_cast<const float4*>(A0 + row*CD + k0 + k4*4);
      if constexpr (MODE==0 || MODE==2){
        float mean = stats[row*2], rst = stats[row*2+1];
        float4 sc = *reinterpret_cast<const float4*>(lnsc + k0 + k4*4);
        float4 bi = *reinterpret_cast<const float4*>(lnbi + k0 + k4*4);
        float4 t;
        t.x = (xv.x-mean)*rst*sc.x + bi.x;
        t.y = (xv.y-mean)*rst*sc.y + bi.y;
        t.z = (xv.z-mean)*rst*sc.z + bi.z;
        t.w = (xv.w-mean)*rst*sc.w + bi.w;
        if constexpr (MODE==2){
          float4 zv = *reinterpret_cast<const float4*>(A1 + row*CD + k0 + k4*4);
          t.x *= zv.x; t.y *= zv.y; t.z *= zv.z; t.w *= zv.w;
        }
        av[p] = t;
      } else {
        av[p] = xv;
      }
    }
    float4 bv[4];
    #pragma unroll
    for (int p=0;p<4;p++){
      int k = kr0 + p*8;
      int col = n0 + n4*4;
      float4 v = make_float4(0.f,0.f,0.f,0.f);
      if (col < Nw) v = *reinterpret_cast<const float4*>(Bm + (k0+k)*Nw + col);
      bv[p] = v;
    }
    __syncthreads();
    #pragma unroll
    for (int p=0;p<BM/32;p++){
      int m = mr0 + p*32;
      As[(k4*4+0)*ASL + m] = av[p].x;
      As[(k4*4+1)*ASL + m] = av[p].y;
      As[(k4*4+2)*ASL + m] = av[p].z;
      As[(k4*4+3)*ASL + m] = av[p].w;
    }
    #pragma unroll
    for (int p=0;p<4;p++){
      int k = kr0 + p*8;
      *reinterpret_cast<float4*>(&Bs[k*BSL + n4*4]) = bv[p];
    }
    __syncthreads();
    #pragma unroll
    for (int k=0;k<BK;k++){
      float a[TM], bfr[TN];
      #pragma unroll
      for (int i=0;i<TM/4;i++)
        *reinterpret_cast<float4*>(&a[i*4]) =
          *reinterpret_cast<const float4*>(&As[k*ASL + ty*TM + i*4]);
      #pragma unroll
      for (int j=0;j<TN/4;j++)
        *reinterpret_cast<float4*>(&bfr[j*4]) =
          *reinterpret_cast<const float4*>(&Bs[k*BSL + tx*TN + j*4]);
      #pragma unroll
      for (int i=0;i<TM;i++)
        #pragma unroll
        for (int j=0;j<TN;j++)
          acc[i][j] = fmaf(a[i], bfr[j], acc[i][j]);
    }
  }
  // epilogue
  #pragma unroll
  for (int i=0;i<TM;i++){
    int row = m0 + ty*TM + i;
    #pragma unroll
    for (int j4=0;j4<TN/4;j4++){
      int col = n0 + tx*TN + j4*4;
      float4 r;
      r.x = acc[i][j4*4+0]; r.y = acc[i][j4*4+1];
      r.z = acc[i][j4*4+2]; r.w = acc[i][j4*4+3];
      if constexpr (MODE==0){
        float4 bb = *reinterpret_cast<const float4*>(bias + col);
        r.x = silu_f(r.x + bb.x); r.y = silu_f(r.y + bb.y);
        r.z = silu_f(r.z + bb.z); r.w = silu_f(r.w + bb.w);
        if (col < CD)
          *reinterpret_cast<float4*>(out0 + row*CD + col) = r;
        else
          *reinterpret_cast<float4*>(out1 + row*CD + (col - CD)) = r;
      } else if constexpr (MODE==1){
        if (col < Nw){
          float4 bb = *reinterpret_cast<const float4*>(bias + col);
          r.x += bb.x; r.y += bb.y; r.z += bb.z; r.w += bb.w;
          *reinterpret_cast<float4*>(out0 + row*SCX + col) = r;
        }
      } else {
        float4 bb = *reinterpret_cast<const float4*>(bias + col);
        float4 xv = *reinterpret_cast<const float4*>(resid + row*CD + col);
        r.x += bb.x + xv.x; r.y += bb.y + xv.y;
        r.z += bb.z + xv.z; r.w += bb.w + xv.w;
        *reinterpret_cast<float4*>(out0 + row*CD + col) = r;
      }
    }
  }
}

// ---------------- scan pass 1: per-chunk local (decay product P, end state) ----------------
// Chunk inputs are identical across the R=4 repetitions, so pass1 covers only L steps.
// Layout of P/He/Hst: [b][j][n][c]  (c fastest -> coalesced across lanes)
__global__ __launch_bounds__(256) void scan_pass1(
    const float* __restrict__ ssm, const float* __restrict__ xg,
    const float* __restrict__ As_log, const float* __restrict__ pbias,
    float* __restrict__ Pw, float* __restrict__ He)
{
  const int b = blockIdx.x >> 8;      // / JC
  const int j = blockIdx.x & 255;
  const int c = threadIdx.x;
  __shared__ float Bt[TC*NS];
  {
    int t = threadIdx.x;              // 256 == TC*NS
    int step = t >> 4, n = t & 15;
    int row = b*LL + j*TC + step;
    Bt[t] = ssm[row*SCX + CD + n];
  }
  __syncthreads();
  float a2[NS], h[NS];
  #pragma unroll
  for (int n=0;n<NS;n++){
    a2[n] = -__expf(As_log[c*NS+n]) * LOG2E;   // A[c][n] * log2(e)
    h[n] = 0.f;
  }
  const float pb = pbias[c];
  float S = 0.f;
  const float* srow = ssm + (b*LL + j*TC)*SCX + c;
  const float* urow = xg  + (b*LL + j*TC)*CD  + c;
  #pragma unroll 4
  for (int t=0;t<TC;t++){
    float dts = srow[t*SCX];
    float u   = urow[t*CD];
    float dt  = softplus_f(dts + pb);
    S += dt;
    float du = dt*u;
    #pragma unroll
    for (int n=0;n<NS;n++){
      h[n] = exp2f(dt*a2[n])*h[n] + du*Bt[t*NS+n];
    }
  }
  int base = ((b*JC + j)*NS)*CD + c;
  #pragma unroll
  for (int n=0;n<NS;n++){
    Pw[base + n*CD] = exp2f(S*a2[n]);          // prod of dA over chunk = exp2(A*sum dt)
    He[base + n*CD] = h[n];
  }
}

// ---------------- hierarchical combine ----------------
// A: per-group composition of GS chunk maps
__global__ __launch_bounds__(256) void combineA(
    const float* __restrict__ Pw, const float* __restrict__ He,
    float* __restrict__ QL, float* __restrict__ EL)
{
  const int id = blockIdx.x;           // (b*GNg + g)*NS + n
  const int n = id & 15;
  const int g = (id >> 4) & 15;
  const int b = id >> 8;
  const int c = threadIdx.x;
  const int jstride = NS*CD;
  int base = ((b*JC + g*GS)*NS + n)*CD + c;
  float q = 1.f, e = 0.f;
  #pragma unroll 4
  for (int i=0;i<GS;i++){
    float p  = Pw[base + i*jstride];
    float he = He[base + i*jstride];
    e = p*e + he;
    q *= p;
  }
  QL[id*CD + c] = q;
  EL[id*CD + c] = e;
}

// B: scan across groups -> group-prefix maps; rep logic -> Srs = sum_r gamma_r * rep_start_r
__global__ __launch_bounds__(256) void combineB(
    const float* __restrict__ QL, const float* __restrict__ EL,
    const float* __restrict__ gamma,
    float* __restrict__ Qg, float* __restrict__ Eg, float* __restrict__ Srs)
{
  const int b = blockIdx.x >> 4, n = blockIdx.x & 15;
  const int c = threadIdx.x;
  float q = 1.f, e = 0.f;
  #pragma unroll
  for (int g=0; g<GNg; g++){
    int idx = ((b*GNg + g)*NS + n)*CD + c;
    Qg[idx] = q; Eg[idx] = e;              // prefix BEFORE group g
    float ql = QL[idx], el = EL[idx];
    e = ql*e + el;
    q = ql*q;
  }
  float PL = q, HL = e;                     // full-rep map
  float g1 = gamma[c*RE+1], g2 = gamma[c*RE+2], g3 = gamma[c*RE+3];
  float s1 = HL;
  float s2 = PL*s1 + HL;
  float s3 = PL*s2 + HL;
  Srs[(b*NS+n)*CD + c] = g1*s1 + g2*s2 + g3*s3;   // rep_start[0]=0
}

// C: expand to per-chunk gamma-combined start state Hst = Q_j*Srs + G*E_j
__global__ __launch_bounds__(256) void combineC(
    const float* __restrict__ Pw, const float* __restrict__ He,
    const float* __restrict__ Qg, const float* __restrict__ Eg,
    const float* __restrict__ Srs, const float* __restrict__ gamma,
    float* __restrict__ Hst)
{
  const int id = blockIdx.x;
  const int n = id & 15;
  const int g = (id >> 4) & 15;
  const int b = id >> 8;
  const int c = threadIdx.x;
  const int jstride = NS*CD;
  float G = gamma[c*RE]+gamma[c*RE+1]+gamma[c*RE+2]+gamma[c*RE+3];
  float srs = Srs[(b*NS+n)*CD + c];
  float q = Qg[id*CD + c], e = Eg[id*CD + c];
  int base = ((b*JC + g*GS)*NS + n)*CD + c;
  #pragma unroll 4
  for (int i=0;i<GS;i++){
    Hst[base + i*jstride] = q*srs + G*e;
    float p  = Pw[base + i*jstride];
    float he = He[base + i*jstride];
    e = p*e + he;
    q *= p;
  }
}

// ---------------- scan pass 2: gamma-combined recurrence H_t = dA*H + G*b; emit y ----------------
__global__ __launch_bounds__(256) void scan_pass2(
    const float* __restrict__ ssm, const float* __restrict__ xg,
    const float* __restrict__ As_log, const float* __restrict__ pbias,
    const float* __restrict__ gamma, const float* __restrict__ Dv,
    const float* __restrict__ Hst, float* __restrict__ yout)
{
  const int b = blockIdx.x >> 8;
  const int j = blockIdx.x & 255;
  const int c = threadIdx.x;
  __shared__ float Bt[TC*NS];
  __shared__ float Ct[TC*NS];
  {
    int t = threadIdx.x;
    int step = t >> 4, n = t & 15;
    int row = b*LL + j*TC + step;
    Bt[t] = ssm[row*SCX + CD + n];
    Ct[t] = ssm[row*SCX + CD + NS + n];
  }
  __syncthreads();
  float a2[NS], h[NS];
  int base = ((b*JC + j)*NS)*CD + c;
  #pragma unroll
  for (int n=0;n<NS;n++){
    a2[n] = -__expf(As_log[c*NS+n]) * LOG2E;
    h[n] = Hst[base + n*CD];
  }
  const float pb = pbias[c];
  const float G  = gamma[c*RE]+gamma[c*RE+1]+gamma[c*RE+2]+gamma[c*RE+3];
  const float GD = G * Dv[c];
  const float* srow = ssm + (b*LL + j*TC)*SCX + c;
  const float* urow = xg  + (b*LL + j*TC)*CD  + c;
  float* yrow = yout + (b*LL + j*TC)*CD + c;
  for (int t=0;t<TC;t++){
    float dts = srow[t*SCX];
    float u   = urow[t*CD];
    float dt  = softplus_f(dts + pb);
    float du  = G*dt*u;
    float y   = GD*u;
    #pragma unroll
    for (int n=0;n<NS;n++){
      float dA = exp2f(dt*a2[n]);
      h[n] = dA*h[n] + du*Bt[t*NS+n];
      y = fmaf(h[n], Ct[t*NS+n], y);
    }
    yrow[t*CD] = y;
  }
}

extern "C" void kernel_launch(void* const* d_in, const int* in_sizes, int n_in,
                              void* d_out, int out_size, void* d_ws, size_t ws_size,
                              hipStream_t stream) {
  const float* x        = (const float*)d_in[0];
  const float* ln_in_s  = (const float*)d_in[2];
  const float* ln_in_b  = (const float*)d_in[3];
  const float* W_in     = (const float*)d_in[4];
  const float* b_in     = (const float*)d_in[5];
  const float* W_ssm    = (const float*)d_in[6];
  const float* b_ssm    = (const float*)d_in[7];
  const float* pbias    = (const float*)d_in[8];
  const float* As_log   = (const float*)d_in[9];
  const float* Ds       = (const float*)d_in[10];
  const float* gamma    = (const float*)d_in[11];
  const float* ln_out_s = (const float*)d_in[12];
  const float* ln_out_b = (const float*)d_in[13];
  const float* W_out    = (const float*)d_in[14];
  const float* b_out    = (const float*)d_in[15];
  float* out = (float*)d_out;

  float* ws = (float*)d_ws;
  float* xg     = ws;            ws += BLr*CD;       // 2,097,152
  float* zz     = ws;            ws += BLr*CD;
  float* ssm    = ws;            ws += BLr*SCX;      // 2,359,296
  float* stats1 = ws;            ws += BLr*2;
  float* stats2 = ws;            ws += BLr*2;
  float* yv     = ws;            ws += BLr*CD;
  float* Pw     = ws;            ws += Bb*JC*NS*CD;  // 2,097,152
  float* He     = ws;            ws += Bb*JC*NS*CD;
  float* Hst    = ws;            ws += Bb*JC*NS*CD;
  float* QL     = ws;            ws += Bb*GNg*NS*CD; // 131,072
  float* EL     = ws;            ws += Bb*GNg*NS*CD;
  float* Qg     = ws;            ws += Bb*GNg*NS*CD;
  float* Eg     = ws;            ws += Bb*GNg*NS*CD;
  float* Srs    = ws;            ws += Bb*NS*CD;     // 8,192

  // 1. LN-in stats
  row_stats<<<BLr/4, 256, 0, stream>>>(x, stats1);
  // 2. proj = silu(LN(x) @ W_in + b_in) -> xg | z
  gemm_k<0,8,8><<<dim3(4,64), 256, 0, stream>>>(x, nullptr, W_in, b_in,
      stats1, ln_in_s, ln_in_b, nullptr, xg, zz, 2*CD);
  // 3. ssm = xg @ W_ssm + b_ssm
  gemm_k<1,8,8><<<dim3(3,64), 256, 0, stream>>>(xg, nullptr, W_ssm, b_ssm,
      nullptr, nullptr, nullptr, nullptr, ssm, nullptr, SCX);
  // 4-6. selective scan (chunked, rep-collapsed)
  scan_pass1<<<Bb*JC, 256, 0, stream>>>(ssm, xg, As_log, pbias, Pw, He);
  combineA<<<Bb*GNg*NS, 256, 0, stream>>>(Pw, He, QL, EL);
  combineB<<<Bb*NS, 256, 0, stream>>>(QL, EL, gamma, Qg, Eg, Srs);
  combineC<<<Bb*GNg*NS, 256, 0, stream>>>(Pw, He, Qg, Eg, Srs, gamma, Hst);
  scan_pass2<<<Bb*JC, 256, 0, stream>>>(ssm, xg, As_log, pbias, gamma, Ds, Hst, yv);
  // 7. LN-out stats
  row_stats<<<BLr/4, 256, 0, stream>>>(yv, stats2);
  // 8. out = x + (z*LN(y)) @ W_out + b_out
  gemm_k<2,4,8><<<dim3(2,128), 256, 0, stream>>>(yv, zz, W_out, b_out,
      stats2, ln_out_s, ln_out_b, x, out, nullptr, CD);
}

// Round 2
// 205.711 us; speedup vs baseline: 1.2300x; 1.2300x over previous
//
#include <hip/hip_runtime.h>
#include <math.h>

#define LOG2E 1.44269504088896f
constexpr int CD  = 256;          // C
constexpr int NS  = 16;           // N states
constexpr int RE  = 4;            // R repeats
constexpr int Bb  = 2;            // batch
constexpr int LL  = 4096;         // L
constexpr int BLr = Bb*LL;        // 8192 rows
constexpr int SCX = 288;          // ssm cols = C + 2N
constexpr int TC  = 16;           // chunk length (steps)
constexpr int JC  = LL/TC;        // 256 chunks per rep
constexpr int GS  = 16;           // combine group size
constexpr int GNg = JC/GS;        // 16 groups

using f32x4  = __attribute__((ext_vector_type(4))) float;
using bf16x8 = __attribute__((ext_vector_type(8))) short;

__device__ __forceinline__ float softplus_f(float v){
  return fmaxf(v, 0.f) + log1pf(__expf(-fabsf(v)));
}
__device__ __forceinline__ float silu_f(float v){
  return v * (1.f/(1.f + __expf(-v)));
}
__device__ __forceinline__ unsigned short f2bf(float f){
  unsigned u = __builtin_bit_cast(unsigned, f);
  unsigned r = (u + 0x7FFFu + ((u >> 16) & 1u)) >> 16;
  return (unsigned short)r;
}

// ---------------- per-row mean/rstd ----------------
__global__ __launch_bounds__(256) void row_stats(const float* __restrict__ X,
                                                 float* __restrict__ stats){
  int row  = blockIdx.x*4 + (threadIdx.x >> 6);
  int lane = threadIdx.x & 63;
  float4 v = reinterpret_cast<const float4*>(X + row*CD)[lane];
  float s  = v.x+v.y+v.z+v.w;
  float s2 = v.x*v.x+v.y*v.y+v.z*v.z+v.w*v.w;
  #pragma unroll
  for (int off = 32; off > 0; off >>= 1){
    s  += __shfl_down(s, off);
    s2 += __shfl_down(s2, off);
  }
  if (lane == 0){
    float m   = s*(1.f/CD);
    float var = s2*(1.f/CD) - m*m;
    stats[row*2+0] = m;
    stats[row*2+1] = rsqrtf(var + 1e-5f);
  }
}

// ---------------- weight prep: W (K x N fp32) -> WT (Npad x K bf16, k-contiguous) ----------------
// 64x64 LDS tile transpose + convert; zero-fill n >= N.
__global__ __launch_bounds__(256) void prep_wt(
    const float* __restrict__ W0, const float* __restrict__ W1,
    const float* __restrict__ W2,
    short* __restrict__ T0, short* __restrict__ T1, short* __restrict__ T2)
{
  int bid = blockIdx.x;
  const float* W; short* T; int N, tilesN;
  if (bid < 32)      { W = W0; T = T0; N = 512; tilesN = 8; }
  else if (bid < 52) { bid -= 32; W = W1; T = T1; N = 288; tilesN = 5; }
  else               { bid -= 52; W = W2; T = T2; N = 256; tilesN = 4; }
  const int kt = bid / tilesN, nt = bid % tilesN;
  __shared__ __align__(16) float Ls[64*65];
  const int t = threadIdx.x;
  {
    const int n4 = t & 15, kr = t >> 4;
    #pragma unroll
    for (int p=0;p<4;p++){
      int k = kr + p*16;
      int ncol = nt*64 + n4*4;
      float4 v = make_float4(0.f,0.f,0.f,0.f);
      if (ncol < N) v = *reinterpret_cast<const float4*>(W + (kt*64+k)*N + ncol);
      Ls[k*65 + n4*4+0] = v.x;
      Ls[k*65 + n4*4+1] = v.y;
      Ls[k*65 + n4*4+2] = v.z;
      Ls[k*65 + n4*4+3] = v.w;
    }
  }
  __syncthreads();
  const int n = t >> 2, kc = (t & 3)*16;
  unsigned short o[16];
  #pragma unroll
  for (int i=0;i<16;i++) o[i] = f2bf(Ls[(kc+i)*65 + n]);
  uint4 u0, u1;
  u0.x = o[0] | (o[1]<<16);   u0.y = o[2] | (o[3]<<16);
  u0.z = o[4] | (o[5]<<16);   u0.w = o[6] | (o[7]<<16);
  u1.x = o[8] | (o[9]<<16);   u1.y = o[10] | (o[11]<<16);
  u1.z = o[12] | (o[13]<<16); u1.w = o[14] | (o[15]<<16);
  short* dst = T + (nt*64 + n)*256 + kt*64 + kc;
  *reinterpret_cast<uint4*>(dst)     = u0;
  *reinterpret_cast<uint4*>(dst + 8) = u1;
}

// ---------------- bf16 MFMA GEMM, BM=128 BN=64 BK=32, fused A-transform + epilogue ----------------
// MODE 0: A = LN(x) on the fly; epi: silu(v+b); cols<256 -> out0 (xg), else out1 (z)
// MODE 1: A = raw xg;           epi: v+b -> out0 (ssm, stride 288, col-masked vs Nw)
// MODE 2: A = z*LN(y);          epi: v+b+resid -> out0 (final out)
template<int MODE>
__global__ __launch_bounds__(256) void gemm_k(
    const float* __restrict__ A0, const float* __restrict__ A1,
    const short* __restrict__ WT, const float* __restrict__ bias,
    const float* __restrict__ stats, const float* __restrict__ lnsc,
    const float* __restrict__ lnbi, const float* __restrict__ resid,
    float* __restrict__ out0, float* __restrict__ out1, int Nw)
{
  constexpr int ASL = 40;               // padded k-stride (bf16) for both tiles
  __shared__ __align__(16) short As[128*ASL];
  __shared__ __align__(16) short Bs[64*ASL];
  const int tid = threadIdx.x;
  const int l  = tid & 63;
  const int w  = tid >> 6;
  const int lr = l & 15;                // fragment row/col index
  const int lq = l >> 4;                // fragment k-quad
  const int n0 = blockIdx.x * 64, m0 = blockIdx.y * 128;

  f32x4 acc[2][4];
  #pragma unroll
  for (int i=0;i<2;i++)
    #pragma unroll
    for (int j=0;j<4;j++) acc[i][j] = (f32x4){0.f,0.f,0.f,0.f};

  const int k4 = tid & 7;   // A staging: float4 col within BK=32
  const int mr = tid >> 3;  // A staging: row 0..31 (4 passes)
  const int bn = tid >> 2;  // B staging: row (n) 0..63
  const int k8 = tid & 3;   // B staging: 8-bf16 chunk within BK

  for (int k0 = 0; k0 < CD; k0 += 32){
    // ---- global loads to regs (with fused A transform + bf16 convert) ----
    ushort4 av[4];
    #pragma unroll
    for (int p=0;p<4;p++){
      int row = m0 + mr + p*32;
      float4 xv = *reinterpret_cast<const float4*>(A0 + row*CD + k0 + k4*4);
      if constexpr (MODE==0 || MODE==2){
        float mean = stats[row*2], rst = stats[row*2+1];
        float4 sc = *reinterpret_cast<const float4*>(lnsc + k0 + k4*4);
        float4 bi = *reinterpret_cast<const float4*>(lnbi + k0 + k4*4);
        xv.x = (xv.x-mean)*rst*sc.x + bi.x;
        xv.y = (xv.y-mean)*rst*sc.y + bi.y;
        xv.z = (xv.z-mean)*rst*sc.z + bi.z;
        xv.w = (xv.w-mean)*rst*sc.w + bi.w;
        if constexpr (MODE==2){
          float4 zv = *reinterpret_cast<const float4*>(A1 + row*CD + k0 + k4*4);
          xv.x *= zv.x; xv.y *= zv.y; xv.z *= zv.z; xv.w *= zv.w;
        }
      }
      av[p].x = f2bf(xv.x); av[p].y = f2bf(xv.y);
      av[p].z = f2bf(xv.z); av[p].w = f2bf(xv.w);
    }
    uint4 bv = *reinterpret_cast<const uint4*>(WT + (n0 + bn)*CD + k0 + k8*8);
    __syncthreads();
    // ---- write LDS ----
    #pragma unroll
    for (int p=0;p<4;p++)
      *reinterpret_cast<ushort4*>(&As[(mr + p*32)*ASL + k4*4]) = av[p];
    *reinterpret_cast<uint4*>(&Bs[bn*ASL + k8*8]) = bv;
    __syncthreads();
    // ---- fragments + MFMA ----
    bf16x8 af[2], bf[4];
    #pragma unroll
    for (int mt=0;mt<2;mt++)
      af[mt] = *reinterpret_cast<const bf16x8*>(&As[(w*32 + mt*16 + lr)*ASL + lq*8]);
    #pragma unroll
    for (int nt=0;nt<4;nt++)
      bf[nt] = *reinterpret_cast<const bf16x8*>(&Bs[(nt*16 + lr)*ASL + lq*8]);
    #pragma unroll
    for (int mt=0;mt<2;mt++)
      #pragma unroll
      for (int nt=0;nt<4;nt++)
        acc[mt][nt] = __builtin_amdgcn_mfma_f32_16x16x32_bf16(af[mt], bf[nt], acc[mt][nt], 0, 0, 0);
  }
  // ---- epilogue: C[row][col], row = (lq*4+reg), col = lr within each 16x16 tile ----
  #pragma unroll
  for (int mt=0;mt<2;mt++){
    int rowb = m0 + w*32 + mt*16 + lq*4;
    #pragma unroll
    for (int nt=0;nt<4;nt++){
      int col = n0 + nt*16 + lr;
      #pragma unroll
      for (int r=0;r<4;r++){
        int row = rowb + r;
        float val = acc[mt][nt][r];
        if constexpr (MODE==0){
          val = silu_f(val + bias[col]);
          if (col < CD) out0[row*CD + col] = val;
          else          out1[row*CD + col - CD] = val;
        } else if constexpr (MODE==1){
          if (col < Nw) out0[row*SCX + col] = val + bias[col];
        } else {
          out0[row*CD + col] = val + bias[col] + resid[row*CD + col];
        }
      }
    }
  }
}

// ---------------- scan pass 1: per-chunk local (decay product P, end state) ----------------
__global__ __launch_bounds__(256) void scan_pass1(
    const float* __restrict__ ssm, const float* __restrict__ xg,
    const float* __restrict__ As_log, const float* __restrict__ pbias,
    float* __restrict__ Pw, float* __restrict__ He)
{
  const int b = blockIdx.x >> 8;
  const int j = blockIdx.x & 255;
  const int c = threadIdx.x;
  __shared__ float Bt[TC*NS];
  {
    int t = threadIdx.x;
    int step = t >> 4, n = t & 15;
    int row = b*LL + j*TC + step;
    Bt[t] = ssm[row*SCX + CD + n];
  }
  __syncthreads();
  float a2[NS], h[NS];
  #pragma unroll
  for (int n=0;n<NS;n++){
    a2[n] = -__expf(As_log[c*NS+n]) * LOG2E;
    h[n] = 0.f;
  }
  const float pb = pbias[c];
  float S = 0.f;
  const float* srow = ssm + (b*LL + j*TC)*SCX + c;
  const float* urow = xg  + (b*LL + j*TC)*CD  + c;
  #pragma unroll 4
  for (int t=0;t<TC;t++){
    float dts = srow[t*SCX];
    float u   = urow[t*CD];
    float dt  = softplus_f(dts + pb);
    S += dt;
    float du = dt*u;
    #pragma unroll
    for (int n=0;n<NS;n++){
      h[n] = exp2f(dt*a2[n])*h[n] + du*Bt[t*NS+n];
    }
  }
  int base = ((b*JC + j)*NS)*CD + c;
  #pragma unroll
  for (int n=0;n<NS;n++){
    Pw[base + n*CD] = exp2f(S*a2[n]);
    He[base + n*CD] = h[n];
  }
}

// ---------------- hierarchical combine ----------------
__global__ __launch_bounds__(256) void combineA(
    const float* __restrict__ Pw, const float* __restrict__ He,
    float* __restrict__ QL, float* __restrict__ EL)
{
  const int id = blockIdx.x;
  const int c = threadIdx.x;
  const int jstride = NS*CD;
  const int n = id & 15;
  const int g = (id >> 4) & 15;
  const int b = id >> 8;
  int base = ((b*JC + g*GS)*NS + n)*CD + c;
  float q = 1.f, e = 0.f;
  #pragma unroll 4
  for (int i=0;i<GS;i++){
    float p  = Pw[base + i*jstride];
    float he = He[base + i*jstride];
    e = p*e + he;
    q *= p;
  }
  QL[id*CD + c] = q;
  EL[id*CD + c] = e;
}

__global__ __launch_bounds__(256) void combineB(
    const float* __restrict__ QL, const float* __restrict__ EL,
    const float* __restrict__ gamma,
    float* __restrict__ Qg, float* __restrict__ Eg, float* __restrict__ Srs)
{
  const int b = blockIdx.x >> 4, n = blockIdx.x & 15;
  const int c = threadIdx.x;
  float q = 1.f, e = 0.f;
  #pragma unroll
  for (int g=0; g<GNg; g++){
    int idx = ((b*GNg + g)*NS + n)*CD + c;
    Qg[idx] = q; Eg[idx] = e;
    float ql = QL[idx], el = EL[idx];
    e = ql*e + el;
    q = ql*q;
  }
  float PL = q, HL = e;
  float g1 = gamma[c*RE+1], g2 = gamma[c*RE+2], g3 = gamma[c*RE+3];
  float s1 = HL;
  float s2 = PL*s1 + HL;
  float s3 = PL*s2 + HL;
  Srs[(b*NS+n)*CD + c] = g1*s1 + g2*s2 + g3*s3;
}

__global__ __launch_bounds__(256) void combineC(
    const float* __restrict__ Pw, const float* __restrict__ He,
    const float* __restrict__ Qg, const float* __restrict__ Eg,
    const float* __restrict__ Srs, const float* __restrict__ gamma,
    float* __restrict__ Hst)
{
  const int id = blockIdx.x;
  const int n = id & 15;
  const int g = (id >> 4) & 15;
  const int b = id >> 8;
  const int c = threadIdx.x;
  const int jstride = NS*CD;
  float G = gamma[c*RE]+gamma[c*RE+1]+gamma[c*RE+2]+gamma[c*RE+3];
  float srs = Srs[(b*NS+n)*CD + c];
  float q = Qg[id*CD + c], e = Eg[id*CD + c];
  int base = ((b*JC + g*GS)*NS + n)*CD + c;
  #pragma unroll 4
  for (int i=0;i<GS;i++){
    Hst[base + i*jstride] = q*srs + G*e;
    float p  = Pw[base + i*jstride];
    float he = He[base + i*jstride];
    e = p*e + he;
    q *= p;
  }
}

// ---------------- scan pass 2 ----------------
__global__ __launch_bounds__(256) void scan_pass2(
    const float* __restrict__ ssm, const float* __restrict__ xg,
    const float* __restrict__ As_log, const float* __restrict__ pbias,
    const float* __restrict__ gamma, const float* __restrict__ Dv,
    const float* __restrict__ Hst, float* __restrict__ yout)
{
  const int b = blockIdx.x >> 8;
  const int j = blockIdx.x & 255;
  const int c = threadIdx.x;
  __shared__ float Bt[TC*NS];
  __shared__ float Ct[TC*NS];
  {
    int t = threadIdx.x;
    int step = t >> 4, n = t & 15;
    int row = b*LL + j*TC + step;
    Bt[t] = ssm[row*SCX + CD + n];
    Ct[t] = ssm[row*SCX + CD + NS + n];
  }
  __syncthreads();
  float a2[NS], h[NS];
  int base = ((b*JC + j)*NS)*CD + c;
  #pragma unroll
  for (int n=0;n<NS;n++){
    a2[n] = -__expf(As_log[c*NS+n]) * LOG2E;
    h[n] = Hst[base + n*CD];
  }
  const float pb = pbias[c];
  const float G  = gamma[c*RE]+gamma[c*RE+1]+gamma[c*RE+2]+gamma[c*RE+3];
  const float GD = G * Dv[c];
  const float* srow = ssm + (b*LL + j*TC)*SCX + c;
  const float* urow = xg  + (b*LL + j*TC)*CD  + c;
  float* yrow = yout + (b*LL + j*TC)*CD + c;
  for (int t=0;t<TC;t++){
    float dts = srow[t*SCX];
    float u   = urow[t*CD];
    float dt  = softplus_f(dts + pb);
    float du  = G*dt*u;
    float y   = GD*u;
    #pragma unroll
    for (int n=0;n<NS;n++){
      float dA = exp2f(dt*a2[n]);
      h[n] = dA*h[n] + du*Bt[t*NS+n];
      y = fmaf(h[n], Ct[t*NS+n], y);
    }
    yrow[t*CD] = y;
  }
}

extern "C" void kernel_launch(void* const* d_in, const int* in_sizes, int n_in,
                              void* d_out, int out_size, void* d_ws, size_t ws_size,
                              hipStream_t stream) {
  const float* x        = (const float*)d_in[0];
  const float* ln_in_s  = (const float*)d_in[2];
  const float* ln_in_b  = (const float*)d_in[3];
  const float* W_in     = (const float*)d_in[4];
  const float* b_in     = (const float*)d_in[5];
  const float* W_ssm    = (const float*)d_in[6];
  const float* b_ssm    = (const float*)d_in[7];
  const float* pbias    = (const float*)d_in[8];
  const float* As_log   = (const float*)d_in[9];
  const float* Ds       = (const float*)d_in[10];
  const float* gamma    = (const float*)d_in[11];
  const float* ln_out_s = (const float*)d_in[12];
  const float* ln_out_b = (const float*)d_in[13];
  const float* W_out    = (const float*)d_in[14];
  const float* b_out    = (const float*)d_in[15];
  float* out = (float*)d_out;

  float* ws = (float*)d_ws;
  float* xg     = ws;            ws += BLr*CD;
  float* zz     = ws;            ws += BLr*CD;
  float* ssm    = ws;            ws += BLr*SCX;
  float* stats1 = ws;            ws += BLr*2;
  float* stats2 = ws;            ws += BLr*2;
  float* yv     = ws;            ws += BLr*CD;
  float* Pw     = ws;            ws += Bb*JC*NS*CD;
  float* He     = ws;            ws += Bb*JC*NS*CD;
  float* Hst    = ws;            ws += Bb*JC*NS*CD;
  float* QL     = ws;            ws += Bb*GNg*NS*CD;
  float* EL     = ws;            ws += Bb*GNg*NS*CD;
  float* Qg     = ws;            ws += Bb*GNg*NS*CD;
  float* Eg     = ws;            ws += Bb*GNg*NS*CD;
  float* Srs    = ws;            ws += Bb*NS*CD;
  short* WT0    = (short*)ws;    // 512*256 bf16
  short* WT1    = WT0 + 512*256; // 320*256 bf16
  short* WT2    = WT1 + 320*256; // 256*256 bf16

  // 0. weight transpose+convert (bf16, [n][k])
  prep_wt<<<68, 256, 0, stream>>>(W_in, W_ssm, W_out, WT0, WT1, WT2);
  // 1. LN-in stats
  row_stats<<<BLr/4, 256, 0, stream>>>(x, stats1);
  // 2. proj = silu(LN(x) @ W_in + b_in) -> xg | z
  gemm_k<0><<<dim3(8,64), 256, 0, stream>>>(x, nullptr, WT0, b_in,
      stats1, ln_in_s, ln_in_b, nullptr, xg, zz, 2*CD);
  // 3. ssm = xg @ W_ssm + b_ssm
  gemm_k<1><<<dim3(5,64), 256, 0, stream>>>(xg, nullptr, WT1, b_ssm,
      nullptr, nullptr, nullptr, nullptr, ssm, nullptr, SCX);
  // 4-6. selective scan (chunked, rep-collapsed)
  scan_pass1<<<Bb*JC, 256, 0, stream>>>(ssm, xg, As_log, pbias, Pw, He);
  combineA<<<Bb*GNg*NS, 256, 0, stream>>>(Pw, He, QL, EL);
  combineB<<<Bb*NS, 256, 0, stream>>>(QL, EL, gamma, Qg, Eg, Srs);
  combineC<<<Bb*GNg*NS, 256, 0, stream>>>(Pw, He, Qg, Eg, Srs, gamma, Hst);
  scan_pass2<<<Bb*JC, 256, 0, stream>>>(ssm, xg, As_log, pbias, gamma, Ds, Hst, yv);
  // 7. LN-out stats
  row_stats<<<BLr/4, 256, 0, stream>>>(yv, stats2);
  // 8. out = x + (z*LN(y)) @ W_out + b_out
  gemm_k<2><<<dim3(4,64), 256, 0, stream>>>(yv, zz, WT2, b_out,
      stats2, ln_out_s, ln_out_b, x, out, nullptr, CD);
}

// Round 4
// 183.874 us; speedup vs baseline: 1.3760x; 1.1188x over previous
//
#include <hip/hip_runtime.h>
#include <math.h>

#define LOG2E 1.44269504088896f
constexpr int CD  = 256;          // C
constexpr int NS  = 16;           // N states
constexpr int RE  = 4;            // R repeats
constexpr int Bb  = 2;            // batch
constexpr int LL  = 4096;         // L
constexpr int BLr = Bb*LL;        // 8192 rows
constexpr int SCX = 288;          // ssm cols = C + 2N
constexpr int TC  = 16;           // chunk length (steps)
constexpr int JC  = LL/TC;        // 256 chunks per rep
constexpr int GS  = 16;           // combine group size
constexpr int GNg = JC/GS;        // 16 groups

using f32x4  = __attribute__((ext_vector_type(4))) float;
using bf16x8 = __attribute__((ext_vector_type(8))) short;

__device__ __forceinline__ float softplus_f(float v){
  return fmaxf(v, 0.f) + log1pf(__expf(-fabsf(v)));
}
__device__ __forceinline__ float silu_f(float v){
  return v * (1.f/(1.f + __expf(-v)));
}
__device__ __forceinline__ unsigned short f2bf(float f){
  unsigned u = __builtin_bit_cast(unsigned, f);
  unsigned r = (u + 0x7FFFu + ((u >> 16) & 1u)) >> 16;
  return (unsigned short)r;
}

// ---------------- fused prep: weight transpose->bf16  +  xn = bf16(LN(x)) ----------------
__global__ __launch_bounds__(256) void prep_fused(
    const float* __restrict__ W0, const float* __restrict__ W1,
    const float* __restrict__ W2,
    short* __restrict__ T0, short* __restrict__ T1, short* __restrict__ T2,
    const float* __restrict__ x, const float* __restrict__ lnsc,
    const float* __restrict__ lnbi, unsigned short* __restrict__ xn)
{
  int bid = blockIdx.x;
  if (bid < 68){
    const float* W; short* T; int N, tilesN;
    if (bid < 32)      { W = W0; T = T0; N = 512; tilesN = 8; }
    else if (bid < 52) { bid -= 32; W = W1; T = T1; N = 288; tilesN = 5; }
    else               { bid -= 52; W = W2; T = T2; N = 256; tilesN = 4; }
    const int kt = bid / tilesN, nt = bid % tilesN;
    __shared__ __align__(16) float Ls[64*65];
    const int t = threadIdx.x;
    {
      const int n4 = t & 15, kr = t >> 4;
      #pragma unroll
      for (int p=0;p<4;p++){
        int k = kr + p*16;
        int ncol = nt*64 + n4*4;
        float4 v = make_float4(0.f,0.f,0.f,0.f);
        if (ncol < N) v = *reinterpret_cast<const float4*>(W + (kt*64+k)*N + ncol);
        Ls[k*65 + n4*4+0] = v.x;
        Ls[k*65 + n4*4+1] = v.y;
        Ls[k*65 + n4*4+2] = v.z;
        Ls[k*65 + n4*4+3] = v.w;
      }
    }
    __syncthreads();
    const int n = t >> 2, kc = (t & 3)*16;
    unsigned short o[16];
    #pragma unroll
    for (int i=0;i<16;i++) o[i] = f2bf(Ls[(kc+i)*65 + n]);
    uint4 u0, u1;
    u0.x = o[0] | (o[1]<<16);   u0.y = o[2] | (o[3]<<16);
    u0.z = o[4] | (o[5]<<16);   u0.w = o[6] | (o[7]<<16);
    u1.x = o[8] | (o[9]<<16);   u1.y = o[10] | (o[11]<<16);
    u1.z = o[12] | (o[13]<<16); u1.w = o[14] | (o[15]<<16);
    short* dst = T + (nt*64 + n)*256 + kt*64 + kc;
    *reinterpret_cast<uint4*>(dst)     = u0;
    *reinterpret_cast<uint4*>(dst + 8) = u1;
    return;
  }
  bid -= 68;
  int row  = bid*4 + (threadIdx.x >> 6);
  int lane = threadIdx.x & 63;
  float4 v = reinterpret_cast<const float4*>(x + row*CD)[lane];
  float s  = v.x+v.y+v.z+v.w;
  float s2 = v.x*v.x+v.y*v.y+v.z*v.z+v.w*v.w;
  #pragma unroll
  for (int off = 32; off > 0; off >>= 1){
    s  += __shfl_xor(s, off);
    s2 += __shfl_xor(s2, off);
  }
  float m   = s*(1.f/CD);
  float rst = rsqrtf(s2*(1.f/CD) - m*m + 1e-5f);
  float4 sc = reinterpret_cast<const float4*>(lnsc)[lane];
  float4 bi = reinterpret_cast<const float4*>(lnbi)[lane];
  ushort4 o;
  o.x = f2bf((v.x-m)*rst*sc.x + bi.x);
  o.y = f2bf((v.y-m)*rst*sc.y + bi.y);
  o.z = f2bf((v.z-m)*rst*sc.z + bi.z);
  o.w = f2bf((v.w-m)*rst*sc.w + bi.w);
  reinterpret_cast<ushort4*>(xn + row*CD)[lane] = o;
}

// ---------------- bf16 MFMA GEMM, BM=128 BN=64 BK=32; A pre-converted bf16 [M][256] ----------------
template<int MODE>
__global__ __launch_bounds__(256) void gemm_k(
    const unsigned short* __restrict__ Abf, const short* __restrict__ WT,
    const float* __restrict__ bias, const float* __restrict__ resid,
    float* __restrict__ out0, float* __restrict__ out1,
    unsigned short* __restrict__ outbf, int Nw)
{
  constexpr int ASL = 40;
  __shared__ __align__(16) short As[128*ASL];
  __shared__ __align__(16) short Bs[64*ASL];
  const int tid = threadIdx.x;
  const int l  = tid & 63;
  const int w  = tid >> 6;
  const int lr = l & 15;
  const int lq = l >> 4;
  const int n0 = blockIdx.x * 64, m0 = blockIdx.y * 128;

  f32x4 acc[2][4];
  #pragma unroll
  for (int i=0;i<2;i++)
    #pragma unroll
    for (int j=0;j<4;j++) acc[i][j] = (f32x4){0.f,0.f,0.f,0.f};

  const int amr = tid >> 1;
  const int akc = (tid & 1) * 16;
  const int bn  = tid >> 2;
  const int bk8 = (tid & 3) * 8;

  for (int k0 = 0; k0 < CD; k0 += 32){
    uint4 a0 = *reinterpret_cast<const uint4*>(Abf + (m0+amr)*CD + k0 + akc);
    uint4 a1 = *reinterpret_cast<const uint4*>(Abf + (m0+amr)*CD + k0 + akc + 8);
    uint4 bv = *reinterpret_cast<const uint4*>(WT + (n0+bn)*CD + k0 + bk8);
    __syncthreads();
    *reinterpret_cast<uint4*>(&As[amr*ASL + akc])     = a0;
    *reinterpret_cast<uint4*>(&As[amr*ASL + akc + 8]) = a1;
    *reinterpret_cast<uint4*>(&Bs[bn*ASL + bk8])      = bv;
    __syncthreads();
    bf16x8 af[2], bf[4];
    #pragma unroll
    for (int mt=0;mt<2;mt++)
      af[mt] = *reinterpret_cast<const bf16x8*>(&As[(w*32 + mt*16 + lr)*ASL + lq*8]);
    #pragma unroll
    for (int nt=0;nt<4;nt++)
      bf[nt] = *reinterpret_cast<const bf16x8*>(&Bs[(nt*16 + lr)*ASL + lq*8]);
    #pragma unroll
    for (int mt=0;mt<2;mt++)
      #pragma unroll
      for (int nt=0;nt<4;nt++)
        acc[mt][nt] = __builtin_amdgcn_mfma_f32_16x16x32_bf16(af[mt], bf[nt], acc[mt][nt], 0, 0, 0);
  }
  #pragma unroll
  for (int mt=0;mt<2;mt++){
    int rowb = m0 + w*32 + mt*16 + lq*4;
    #pragma unroll
    for (int nt=0;nt<4;nt++){
      int col = n0 + nt*16 + lr;
      #pragma unroll
      for (int r=0;r<4;r++){
        int row = rowb + r;
        float val = acc[mt][nt][r];
        if constexpr (MODE==0){
          val = silu_f(val + bias[col]);
          if (col < CD){
            out0[row*CD + col] = val;
            outbf[row*CD + col] = f2bf(val);
          } else {
            out1[row*CD + col - CD] = val;
          }
        } else if constexpr (MODE==1){
          if (col < Nw) out0[row*SCX + col] = val + bias[col];
        } else {
          out0[row*CD + col] = val + bias[col] + resid[row*CD + col];
        }
      }
    }
  }
}

// ---------------- scan pass 1: per-chunk local (decay product, end state) -> PH ----------------
__global__ __launch_bounds__(256) void scan_pass1(
    const float* __restrict__ ssm, const float* __restrict__ xg,
    const float* __restrict__ As_log, const float* __restrict__ pbias,
    float2* __restrict__ PH)
{
  const int b = blockIdx.x >> 8;
  const int j = blockIdx.x & 255;
  const int c = threadIdx.x;
  __shared__ float Bt[TC*NS];
  {
    int step = c >> 4, n = c & 15;
    Bt[c] = ssm[(b*LL + j*TC + step)*SCX + CD + n];
  }
  __syncthreads();
  float a2[NS], h[NS];
  #pragma unroll
  for (int n=0;n<NS;n++){
    a2[n] = -__expf(As_log[c*NS+n]) * LOG2E;
    h[n] = 0.f;
  }
  const float pb = pbias[c];
  float S = 0.f;
  const float* srow = ssm + (b*LL + j*TC)*SCX + c;
  const float* urow = xg  + (b*LL + j*TC)*CD  + c;
  #pragma unroll 4
  for (int t=0;t<TC;t++){
    float dt = softplus_f(srow[t*SCX] + pb);
    float du = dt * urow[t*CD];
    S += dt;
    #pragma unroll
    for (int n=0;n<NS;n++)
      h[n] = exp2f(dt*a2[n])*h[n] + du*Bt[t*NS+n];
  }
  int base = ((b*JC + j)*NS)*CD + c;
  #pragma unroll
  for (int n=0;n<NS;n++)
    PH[base + n*CD] = make_float2(exp2f(S*a2[n]), h[n]);
}

// ---------------- combineA: per-group composition of GS chunk maps ----------------
__global__ __launch_bounds__(256) void combineA(
    const float2* __restrict__ PH, float2* __restrict__ QE)
{
  const int id = blockIdx.x;           // b*256 + g*16 + n
  const int n = id & 15;
  const int g = (id >> 4) & 15;
  const int b = id >> 8;
  const int c = threadIdx.x;
  const int jstride = NS*CD;
  int base = ((b*JC + g*GS)*NS + n)*CD + c;
  float q = 1.f, e = 0.f;
  #pragma unroll 4
  for (int i=0;i<GS;i++){
    float2 ph = PH[base + i*jstride];
    e = ph.x*e + ph.y;
    q *= ph.x;
  }
  QE[id*CD + c] = make_float2(q, e);
}

// ---------------- combineBC: redundant group-scan + rep collapse + per-chunk start states ----------------
__global__ __launch_bounds__(256) void combineBC(
    const float2* __restrict__ QE, const float2* __restrict__ PH,
    const float* __restrict__ gamma, float* __restrict__ Hst)
{
  const int id = blockIdx.x;           // b*256 + g*16 + n
  const int n = id & 15;
  const int g = (id >> 4) & 15;
  const int b = id >> 8;
  const int c = threadIdx.x;
  const int jstride = NS*CD;
  float q = 1.f, e = 0.f, qpre = 1.f, epre = 0.f;
  #pragma unroll
  for (int gi=0; gi<GNg; gi++){
    if (gi == g){ qpre = q; epre = e; }
    float2 qe = QE[((b*GNg + gi)*NS + n)*CD + c];
    e = qe.x*e + qe.y;
    q = qe.x*q;
  }
  float PL = q, HL = e;                 // full-rep map
  float g1 = gamma[c*RE+1], g2 = gamma[c*RE+2], g3 = gamma[c*RE+3];
  float s1 = HL;
  float s2 = PL*s1 + HL;
  float s3 = PL*s2 + HL;
  float srs = g1*s1 + g2*s2 + g3*s3;    // sum_r gamma_r * rep_start_r (rep 0 start = 0)
  float G   = gamma[c*RE] + g1 + g2 + g3;
  q = qpre; e = epre;
  int base = ((b*JC + g*GS)*NS + n)*CD + c;
  #pragma unroll 4
  for (int i=0;i<GS;i++){
    Hst[base + i*jstride] = q*srs + G*e;
    float2 ph = PH[base + i*jstride];
    e = ph.x*e + ph.y;
    q = ph.x*q;
  }
}

// ---------------- scan pass 2 + out-LN + z-gate -> Ag (bf16) ----------------
__global__ __launch_bounds__(256) void scan_pass2f(
    const float* __restrict__ ssm, const float* __restrict__ xg,
    const float* __restrict__ zz,
    const float* __restrict__ As_log, const float* __restrict__ pbias,
    const float* __restrict__ gamma, const float* __restrict__ Dv,
    const float* __restrict__ lnsc, const float* __restrict__ lnbi,
    const float* __restrict__ Hst, unsigned short* __restrict__ Ag)
{
  const int b = blockIdx.x >> 8;
  const int j = blockIdx.x & 255;
  const int c = threadIdx.x;
  __shared__ float Bt[TC*NS];
  __shared__ float Ct[TC*NS];
  __shared__ float ysh[TC*CD];
  {
    int step = c >> 4, n = c & 15;
    int row = b*LL + j*TC + step;
    Bt[c] = ssm[row*SCX + CD + n];
    Ct[c] = ssm[row*SCX + CD + NS + n];
  }
  __syncthreads();
  float a2[NS], h[NS];
  int base = ((b*JC + j)*NS)*CD + c;
  #pragma unroll
  for (int n=0;n<NS;n++){
    a2[n] = -__expf(As_log[c*NS+n]) * LOG2E;
    h[n] = Hst[base + n*CD];
  }
  const float pb = pbias[c];
  const float G  = gamma[c*RE]+gamma[c*RE+1]+gamma[c*RE+2]+gamma[c*RE+3];
  const float GD = G * Dv[c];
  const float* srow = ssm + (b*LL + j*TC)*SCX + c;
  const float* urow = xg  + (b*LL + j*TC)*CD  + c;
  for (int t=0;t<TC;t++){
    float u  = urow[t*CD];
    float dt = softplus_f(srow[t*SCX] + pb);
    float du = G*dt*u;
    float y  = GD*u;
    #pragma unroll
    for (int n=0;n<NS;n++){
      h[n] = exp2f(dt*a2[n])*h[n] + du*Bt[t*NS+n];
      y = fmaf(h[n], Ct[t*NS+n], y);
    }
    ysh[t*CD + c] = y;
  }
  __syncthreads();
  const int w = c >> 6, lane = c & 63;
  #pragma unroll
  for (int q=0;q<4;q++){
    int rw = w*4 + q;
    float4 yv = *reinterpret_cast<const float4*>(&ysh[rw*CD + lane*4]);
    float s  = yv.x+yv.y+yv.z+yv.w;
    float s2 = yv.x*yv.x+yv.y*yv.y+yv.z*yv.z+yv.w*yv.w;
    #pragma unroll
    for (int off = 32; off > 0; off >>= 1){
      s  += __shfl_xor(s, off);
      s2 += __shfl_xor(s2, off);
    }
    float m   = s*(1.f/CD);
    float rst = rsqrtf(s2*(1.f/CD) - m*m + 1e-5f);
    int grow = b*LL + j*TC + rw;
    float4 sc = reinterpret_cast<const float4*>(lnsc)[lane];
    float4 bi = reinterpret_cast<const float4*>(lnbi)[lane];
    float4 zv = reinterpret_cast<const float4*>(zz + grow*CD)[lane];
    ushort4 o;
    o.x = f2bf(zv.x*((yv.x-m)*rst*sc.x + bi.x));
    o.y = f2bf(zv.y*((yv.y-m)*rst*sc.y + bi.y));
    o.z = f2bf(zv.z*((yv.z-m)*rst*sc.z + bi.z));
    o.w = f2bf(zv.w*((yv.w-m)*rst*sc.w + bi.w));
    reinterpret_cast<ushort4*>(Ag + grow*CD)[lane] = o;
  }
}

extern "C" void kernel_launch(void* const* d_in, const int* in_sizes, int n_in,
                              void* d_out, int out_size, void* d_ws, size_t ws_size,
                              hipStream_t stream) {
  const float* x        = (const float*)d_in[0];
  const float* ln_in_s  = (const float*)d_in[2];
  const float* ln_in_b  = (const float*)d_in[3];
  const float* W_in     = (const float*)d_in[4];
  const float* b_in     = (const float*)d_in[5];
  const float* W_ssm    = (const float*)d_in[6];
  const float* b_ssm    = (const float*)d_in[7];
  const float* pbias    = (const float*)d_in[8];
  const float* As_log   = (const float*)d_in[9];
  const float* Ds       = (const float*)d_in[10];
  const float* gamma    = (const float*)d_in[11];
  const float* ln_out_s = (const float*)d_in[12];
  const float* ln_out_b = (const float*)d_in[13];
  const float* W_out    = (const float*)d_in[14];
  const float* b_out    = (const float*)d_in[15];
  float* out = (float*)d_out;

  float* ws = (float*)d_ws;
  float* xg   = ws;              ws += BLr*CD;
  float* zz   = ws;              ws += BLr*CD;
  float* ssm  = ws;              ws += BLr*SCX;
  float2* PH  = (float2*)ws;     ws += 2*Bb*JC*NS*CD;
  float2* QE  = (float2*)ws;     ws += 2*Bb*GNg*NS*CD;
  float* Hst  = ws;              ws += Bb*JC*NS*CD;
  unsigned short* xn   = (unsigned short*)ws; ws += BLr*CD/2;
  unsigned short* xgbf = (unsigned short*)ws; ws += BLr*CD/2;
  unsigned short* Ag   = (unsigned short*)ws; ws += BLr*CD/2;
  short* WT0 = (short*)ws;
  short* WT1 = WT0 + 512*256;
  short* WT2 = WT1 + 320*256;

  // 1. weight prep + xn = bf16(LN(x))
  prep_fused<<<68 + BLr/4, 256, 0, stream>>>(W_in, W_ssm, W_out, WT0, WT1, WT2,
      x, ln_in_s, ln_in_b, xn);
  // 2. proj = silu(xn @ W_in^T + b_in) -> xg (f32+bf16) | zz
  gemm_k<0><<<dim3(8,64), 256, 0, stream>>>(xn, WT0, b_in, nullptr,
      xg, zz, xgbf, 2*CD);
  // 3. ssm = xg @ W_ssm^T + b_ssm
  gemm_k<1><<<dim3(5,64), 256, 0, stream>>>(xgbf, WT1, b_ssm, nullptr,
      ssm, nullptr, nullptr, SCX);
  // 4. chunk-local scans
  scan_pass1<<<Bb*JC, 256, 0, stream>>>(ssm, xg, As_log, pbias, PH);
  // 5. group composition
  combineA<<<Bb*GNg*NS, 256, 0, stream>>>(PH, QE);
  // 6. group-scan + rep collapse + per-chunk start states
  combineBC<<<Bb*GNg*NS, 256, 0, stream>>>(QE, PH, gamma, Hst);
  // 7. final recurrence + out-LN + z-gate -> Ag
  scan_pass2f<<<Bb*JC, 256, 0, stream>>>(ssm, xg, zz, As_log, pbias, gamma, Ds,
      ln_out_s, ln_out_b, Hst, Ag);
  // 8. out = x + Ag @ W_out^T + b_out
  gemm_k<2><<<dim3(4,64), 256, 0, stream>>>(Ag, WT2, b_out, x,
      out, nullptr, nullptr, CD);
}